// Round 7
// baseline (426.146 us; speedup 1.0000x reference)
//
#include <hip/hip_runtime.h>

typedef _Float16 half_t;
typedef __attribute__((ext_vector_type(4))) _Float16 half4;
typedef __attribute__((ext_vector_type(8))) _Float16 half8;
typedef __attribute__((ext_vector_type(4))) float f32x4;

#define BATCH  16384
#define BASE   1008
#define BASEP  1024
#define NB     5
#define ROWS_P 17024      // 16384 + 5*128 (segment alignment slack)
#define MT_DENSE 133      // ROWS_P / 128
#define NBLK   64         // BATCH / 256

__constant__ int d_sizes[NB] = {36, 72, 144, 288, 1008};
__constant__ int d_ka[NB]    = {64, 96, 160, 288, 1024};   // align32(s)

__device__ __forceinline__ int bucket_of(int s) {
    return (s == 36) ? 0 : (s == 72) ? 1 : (s == 144) ? 2 : (s == 288) ? 3 : 4;
}

// ---------------- ws layout (bytes) ----------------
// meta: [0..4]=cnt, [5..9]=seg_start (128-aligned)
constexpr size_t OFF_META = 0;                                   // 256 B reserved
constexpr size_t OFF_PERM = 256;                                 // ROWS_P ints
constexpr size_t OFF_RANK = OFF_PERM + (size_t)ROWS_P * 4;       // BATCH ints
constexpr size_t OFF_POS  = OFF_RANK + (size_t)BATCH * 4;        // BATCH ints
constexpr size_t OFF_BLKT = OFF_POS  + (size_t)BATCH * 4;        // NBLK*NB ints
constexpr size_t OFF_BLKB = OFF_BLKT + (size_t)NBLK * NB * 4;    // NBLK*NB ints
constexpr size_t OFF_XH   = (OFF_BLKB + (size_t)NBLK * NB * 4 + 255) & ~(size_t)255;
constexpr size_t SZ1024   = (size_t)ROWS_P * 1024 * 2;
constexpr size_t OFF_E    = OFF_XH + SZ1024;                     // fp16 [ROWS_P][1024]
constexpr size_t OFF_B512 = OFF_E + SZ1024;                      // fp16 [ROWS_P][512]
constexpr size_t OFF_C256 = OFF_B512 + (size_t)ROWS_P * 512 * 2; // fp16 [ROWS_P][256]
constexpr size_t OFF_D128 = OFF_C256 + (size_t)ROWS_P * 256 * 2; // fp16 [ROWS_P][128]
constexpr size_t OFF_WIN  = OFF_D128 + (size_t)ROWS_P * 128 * 2; // fp16 [5][1024][1024]
constexpr size_t OFF_WOUT = OFF_WIN  + (size_t)NB * 1024 * 1024 * 2;
constexpr size_t OFF_WE1  = OFF_WOUT + (size_t)NB * 1024 * 1024 * 2; // [512][1024]
constexpr size_t OFF_WE2  = OFF_WE1 + (size_t)512 * 1024 * 2;        // [256][512]
constexpr size_t OFF_WE3  = OFF_WE2 + (size_t)256 * 512 * 2;         // [128][256]
constexpr size_t OFF_WD1  = OFF_WE3 + (size_t)128 * 256 * 2;         // [256][128]
constexpr size_t OFF_WD2  = OFF_WD1 + (size_t)256 * 128 * 2;         // [512][256]
constexpr size_t OFF_WD3  = OFF_WD2 + (size_t)512 * 256 * 2;         // [1024][512]
constexpr size_t WS_NEED  = OFF_WD3 + (size_t)1024 * 512 * 2;        // ~118.4 MiB

// ---------------- deterministic permutation (no atomics anywhere) ----------------
__global__ void rank_kernel(const int* __restrict__ seq, int* __restrict__ rankb,
                            int* __restrict__ blk_tot) {
    __shared__ int wcnt[4][NB];
    __shared__ int wbase[4][NB];
    const int tid = threadIdx.x, lane = tid & 63, wave = tid >> 6;
    const int b = blockIdx.x * 256 + tid;
    const int k = bucket_of(seq[b]);
    unsigned long long same = 0;
#pragma unroll
    for (int kk = 0; kk < NB; kk++) {
        unsigned long long mk = __ballot(k == kk);
        if (lane == 0) wcnt[wave][kk] = __popcll(mk);
        if (k == kk) same = mk;
    }
    const int lr = __popcll(same & ((1ull << lane) - 1ull));
    __syncthreads();
    if (tid < NB) {                       // tid = bucket index
        int s = 0;
#pragma unroll
        for (int w = 0; w < 4; w++) { wbase[w][tid] = s; s += wcnt[w][tid]; }
        blk_tot[blockIdx.x * NB + tid] = s;
    }
    __syncthreads();
    rankb[b] = wbase[wave][k] + lr;
}

__global__ void base_kernel(const int* __restrict__ blk_tot, int* __restrict__ meta,
                            int* __restrict__ blkbase) {
    __shared__ int tot[NB], seg[NB];
    const int tid = threadIdx.x;
    if (tid < NB) {
        int s = 0;
        for (int blk = 0; blk < NBLK; blk++) {
            blkbase[blk * NB + tid] = s;
            s += blk_tot[blk * NB + tid];
        }
        tot[tid] = s;
    }
    __syncthreads();
    if (tid == 0) {
        int off = 0;
        for (int kk = 0; kk < NB; kk++) {
            seg[kk] = off;
            meta[kk] = tot[kk];
            meta[5 + kk] = off;
            off += (tot[kk] + 127) & ~127;
        }
    }
    __syncthreads();
    if (tid < NB)
        for (int blk = 0; blk < NBLK; blk++) blkbase[blk * NB + tid] += seg[tid];
}

__global__ void finalize_kernel(const int* __restrict__ seq, const int* __restrict__ rankb,
                                const int* __restrict__ blkbase, int* __restrict__ perm,
                                int* __restrict__ pos) {
    const int b = blockIdx.x * 256 + threadIdx.x;
    const int k = bucket_of(seq[b]);
    const int p = blkbase[blockIdx.x * NB + k] + rankb[b];
    perm[p] = b;
    pos[b] = p;
}

// Zero xh segment-padding rows so no GEMM input is ever read-before-write.
__global__ void zero_xh_pad(const int* __restrict__ meta, half_t* __restrict__ xh) {
    const int kb = blockIdx.y;
    const int cnt = meta[kb];
    const int cnt_pad = (cnt + 127) & ~127;
    const int r = cnt + blockIdx.x;
    if (r >= cnt_pad) return;
    const int row = meta[5 + kb] + r;
    half4 z; z.x = z.y = z.z = z.w = (half_t)0.0f;
    *reinterpret_cast<half4*>(xh + (size_t)row * BASEP + threadIdx.x * 4) = z;
}

// Pure coalesced convert+scatter: no atomics, no syncthreads.
__global__ void copy_convert_kernel(const float* __restrict__ x, const int* __restrict__ pos,
                                    half_t* __restrict__ xh) {
    for (int b = blockIdx.x; b < BATCH; b += gridDim.x) {
        int p = pos[b];
        int c = threadIdx.x * 4;  // 0..1020
        half4 o4;
        if (c < BASE) {
            float4 v = *reinterpret_cast<const float4*>(x + (size_t)b * BASE + c);
            o4.x = (half_t)v.x; o4.y = (half_t)v.y; o4.z = (half_t)v.z; o4.w = (half_t)v.w;
        } else {
            o4.x = o4.y = o4.z = o4.w = (half_t)0.0f;
        }
        *reinterpret_cast<half4*>(xh + (size_t)p * BASEP + c) = o4;
    }
}

// ONE fused weight-conversion kernel: 16 jobs (Win x5, Wout x5, 6 dense mats).
// Win job z: only cols < ka[z] are ever read by expand -> skip others.
// Wout job z: only rows < align128(s_z) are ever read by contract.
__global__ void conv_all(const float* __restrict__ Win, const float* __restrict__ Wout,
                         const float* __restrict__ We1, const float* __restrict__ We2,
                         const float* __restrict__ We3, const float* __restrict__ Wd1,
                         const float* __restrict__ Wd2, const float* __restrict__ Wd3,
                         char* __restrict__ ws) {
    const int j = blockIdx.y;
    const float* src; half_t* dst; int R, C, cshift, climit, rlimit;
    if (j < 5) {
        src = Win + (size_t)j * 1008 * 1008;
        dst = (half_t*)(ws + OFF_WIN) + (size_t)j * 1024 * 1024;
        R = 1008; C = 1008; cshift = 10; climit = d_ka[j]; rlimit = 1024;
    } else if (j < 10) {
        int z = j - 5;
        src = Wout + (size_t)z * 1008 * 1008;
        dst = (half_t*)(ws + OFF_WOUT) + (size_t)z * 1024 * 1024;
        R = 1008; C = 1008; cshift = 10; climit = 1024; rlimit = (d_sizes[z] + 127) & ~127;
    } else {
        switch (j) {
        case 10: src = We1; dst = (half_t*)(ws + OFF_WE1); R = 512;  C = 1008; cshift = 10; rlimit = 512;  break;
        case 11: src = We2; dst = (half_t*)(ws + OFF_WE2); R = 256;  C = 512;  cshift = 9;  rlimit = 256;  break;
        case 12: src = We3; dst = (half_t*)(ws + OFF_WE3); R = 128;  C = 256;  cshift = 8;  rlimit = 128;  break;
        case 13: src = Wd1; dst = (half_t*)(ws + OFF_WD1); R = 256;  C = 128;  cshift = 7;  rlimit = 256;  break;
        case 14: src = Wd2; dst = (half_t*)(ws + OFF_WD2); R = 512;  C = 256;  cshift = 8;  rlimit = 512;  break;
        default: src = Wd3; dst = (half_t*)(ws + OFF_WD3); R = 1008; C = 512;  cshift = 9;  rlimit = 1024; break;
        }
        climit = 1 << cshift;
    }
    const int Cp = 1 << cshift;
    const int total = rlimit << cshift;
    for (int i = blockIdx.x * blockDim.x + threadIdx.x; i < total; i += gridDim.x * blockDim.x) {
        int r = i >> cshift, c = i & (Cp - 1);
        if (c >= climit) continue;
        float v = (r < R && c < C) ? src[(size_t)r * C + c] : 0.0f;
        dst[i] = (half_t)v;
    }
}

// ---------------- GEMM ----------------
// 128x128 tile, BK=32, 4 waves. 3-buffer LDS pipeline, depth-2 prefetch,
// counted vmcnt (T4), ONE raw s_barrier per K-step.
// T2 XOR-swizzle (both-sides, rule 21): LDS slot (row,ch) holds
// A[row][k0 + (ch ^ ((row>>1)&3))*8] via pre-swizzled GLOBAL source (LDS dest
// linear for global_load_lds); reads use kcs = (kc ^ ((fr>>1)&3))*8 -> each
// 16-lane phase spreads across all 8 bank-quads (was 2 -> 4x serialization).
// MODE 0: dense   MODE 1: expand (per-bucket K=ka)
// MODE 2: contract (scatter fp32); tiles with ntile*128 >= s_k store bias only
//         -> d_out fully covered, no memset needed.
template <int MODE, bool RELU>
__global__ __launch_bounds__(256)
void gemm_k(const half_t* __restrict__ Abase, const half_t* __restrict__ Wbase,
            const float* __restrict__ biasbase, half_t* __restrict__ Obase,
            float* __restrict__ out32, const int* __restrict__ meta,
            const int* __restrict__ perm, int Kdense, int Npad, int Nreal) {
    const int tid  = threadIdx.x;
    const int lane = tid & 63;
    const int wave = tid >> 6;
    const int mtile = blockIdx.x, ntile = blockIdx.y;

    int K, ld, rowbase, cnt = 0;
    const half_t* A;
    const half_t* W;
    const float* bias;
    if (MODE == 0) {
        K = Kdense; ld = Kdense;
        rowbase = mtile * 128;
        A = Abase + (size_t)rowbase * ld;
        W = Wbase + (size_t)ntile * 128 * ld;
        bias = biasbase;
    } else {
        int kb = blockIdx.z;
        cnt = meta[kb];
        int cnt_pad = (cnt + 127) & ~127;
        if (mtile * 128 >= cnt_pad) return;
        ld = BASEP;
        K = (MODE == 1) ? d_ka[kb] : BASEP;
        rowbase = meta[5 + kb] + mtile * 128;
        A = Abase + (size_t)rowbase * BASEP;
        W = Wbase + (size_t)kb * BASEP * BASEP + (size_t)ntile * 128 * BASEP;
        bias = biasbase + kb * BASE;
    }

    const int wr = (wave >> 1) * 64;   // wave's row quadrant
    const int wc = (wave & 1) * 64;    // wave's col quadrant
    const int fr = lane & 15;
    const int kc = lane >> 4;          // k-chunk 0..3
    const int kcs = (kc ^ ((fr >> 1) & 3)) * 8;  // swizzled half-offset in row
    const int wbase = tid & ~63;       // linear idx of lane0 of this wave

    // bias-only tiles (contract, cols >= s_k): reference output = bout there.
    if (MODE == 2 && ntile * 128 >= d_sizes[blockIdx.z]) {
#pragma unroll
        for (int m = 0; m < 4; m++)
#pragma unroll
            for (int j = 0; j < 4; j++) {
                int r = wr + m * 16 + kc * 4 + j;
                if (mtile * 128 + r < cnt) {
                    int orig = perm[rowbase + r];
#pragma unroll
                    for (int n = 0; n < 4; n++) {
                        int col = ntile * 128 + wc + n * 16 + fr;
                        if (col < BASE)
                            out32[(size_t)orig * BASE + col] = bias[col];
                    }
                }
            }
        return;
    }

    __shared__ __align__(16) half_t As[3][128 * 32];
    __shared__ __align__(16) half_t Bs[3][128 * 32];

    f32x4 acc[4][4];
#pragma unroll
    for (int m = 0; m < 4; m++)
#pragma unroll
        for (int n = 0; n < 4; n++)
            acc[m][n] = (f32x4){0.f, 0.f, 0.f, 0.f};

    // Each STAGE = exactly 4 global_load_lds instructions per wave (vmcnt +4).
    // Global source column pre-swizzled: chunk ch at slot (row,ch) fetches
    // col (ch ^ ((row>>1)&3))*8 -- permutation stays within the row's 64 B.
#define STAGE(buf, kk)                                                                        \
    do {                                                                                      \
        _Pragma("unroll")                                                                     \
        for (int i_ = 0; i_ < 2; i_++) {                                                      \
            int idx_ = i_ * 256 + tid;                                                        \
            int row_ = idx_ >> 2;                                                             \
            int chs_ = (idx_ & 3) ^ ((idx_ >> 3) & 3);                                        \
            const half_t* ga_ = A + (size_t)row_ * ld + ((kk) + chs_ * 8);                    \
            const half_t* gb_ = W + (size_t)row_ * ld + ((kk) + chs_ * 8);                    \
            half_t* la_ = &As[buf][(size_t)(i_ * 256 + wbase) * 8];                           \
            half_t* lb_ = &Bs[buf][(size_t)(i_ * 256 + wbase) * 8];                           \
            __builtin_amdgcn_global_load_lds((__attribute__((address_space(1))) void*)(ga_),  \
                                             (__attribute__((address_space(3))) void*)(la_),  \
                                             16, 0, 0);                                       \
            __builtin_amdgcn_global_load_lds((__attribute__((address_space(1))) void*)(gb_),  \
                                             (__attribute__((address_space(3))) void*)(lb_),  \
                                             16, 0, 0);                                       \
        }                                                                                     \
    } while (0)

    const int NI = K >> 5;             // K/32 iterations (K is a multiple of 32)
    STAGE(0, 0);
    if (NI > 1) STAGE(1, 32);

    int cur = 0;
    for (int i = 0; i < NI; i++) {
        // counted wait: my tile-i loads done (4 = tile i+1's loads may remain)
        if (i + 1 < NI) asm volatile("s_waitcnt vmcnt(4)" ::: "memory");
        else            asm volatile("s_waitcnt vmcnt(0)" ::: "memory");
        __builtin_amdgcn_s_barrier();          // all waves' tile-i loads landed
        asm volatile("" ::: "memory");         // pin LDS reads below the barrier

        half8 af[4], bf[4];
#pragma unroll
        for (int m = 0; m < 4; m++)
            af[m] = *reinterpret_cast<const half8*>(&As[cur][(wr + m * 16 + fr) * 32 + kcs]);
#pragma unroll
        for (int n = 0; n < 4; n++)
            bf[n] = *reinterpret_cast<const half8*>(&Bs[cur][(wc + n * 16 + fr) * 32 + kcs]);
#pragma unroll
        for (int m = 0; m < 4; m++)
#pragma unroll
            for (int n = 0; n < 4; n++)
                acc[m][n] = __builtin_amdgcn_mfma_f32_16x16x32_f16(af[m], bf[n], acc[m][n], 0, 0, 0);

        if (i + 2 < NI) {
            int nxt = cur + 2; if (nxt >= 3) nxt -= 3;
            STAGE(nxt, (i + 2) * 32);          // overwrites tile i-1's buffer (safe)
        }
        cur = (cur + 1 == 3) ? 0 : cur + 1;
    }
#undef STAGE

    // epilogue: D row = (lane>>4)*4 + j, col = lane&15  (m89-verified layout)
    float bv[4];
#pragma unroll
    for (int n = 0; n < 4; n++) {
        int col = ntile * 128 + wc + n * 16 + fr;
        bv[n] = (col < Nreal) ? bias[col] : 0.0f;
    }
#pragma unroll
    for (int m = 0; m < 4; m++) {
#pragma unroll
        for (int j = 0; j < 4; j++) {
            int r = wr + m * 16 + kc * 4 + j;
#pragma unroll
            for (int n = 0; n < 4; n++) {
                float v = acc[m][n][j] + bv[n];
                if (RELU) v = fmaxf(v, 0.0f);
                int c = wc + n * 16 + fr;
                if (MODE == 2) {
                    if (mtile * 128 + r < cnt) {
                        int col = ntile * 128 + c;
                        if (col < BASE) {
                            int orig = perm[rowbase + r];
                            out32[(size_t)orig * BASE + col] = v;
                        }
                    }
                } else {
                    Obase[(size_t)(rowbase + r) * Npad + ntile * 128 + c] = (half_t)v;
                }
            }
        }
    }
}

// ---------------- launch ----------------
extern "C" void kernel_launch(void* const* d_in, const int* in_sizes, int n_in,
                              void* d_out, int out_size, void* d_ws, size_t ws_size,
                              hipStream_t stream) {
    (void)in_sizes; (void)n_in; (void)out_size;
    if (ws_size < WS_NEED) return;

    const float* x    = (const float*)d_in[0];
    const int*   seq  = (const int*)d_in[1];
    const float* Win  = (const float*)d_in[2];
    const float* bin_ = (const float*)d_in[3];
    const float* Wout = (const float*)d_in[4];
    const float* bout = (const float*)d_in[5];
    const float* We1  = (const float*)d_in[6];  const float* be1 = (const float*)d_in[7];
    const float* We2  = (const float*)d_in[8];  const float* be2 = (const float*)d_in[9];
    const float* We3  = (const float*)d_in[10]; const float* be3 = (const float*)d_in[11];
    const float* Wd1  = (const float*)d_in[12]; const float* bd1 = (const float*)d_in[13];
    const float* Wd2  = (const float*)d_in[14]; const float* bd2 = (const float*)d_in[15];
    const float* Wd3  = (const float*)d_in[16]; const float* bd3 = (const float*)d_in[17];

    char* ws = (char*)d_ws;
    int*    meta   = (int*)(ws + OFF_META);
    int*    perm   = (int*)(ws + OFF_PERM);
    int*    rankb  = (int*)(ws + OFF_RANK);
    int*    pos    = (int*)(ws + OFF_POS);
    int*    blkt   = (int*)(ws + OFF_BLKT);
    int*    blkb   = (int*)(ws + OFF_BLKB);
    half_t* xh   = (half_t*)(ws + OFF_XH);
    half_t* E    = (half_t*)(ws + OFF_E);
    half_t* B512 = (half_t*)(ws + OFF_B512);
    half_t* C256 = (half_t*)(ws + OFF_C256);
    half_t* D128 = (half_t*)(ws + OFF_D128);
    half_t* winh = (half_t*)(ws + OFF_WIN);
    half_t* wouth= (half_t*)(ws + OFF_WOUT);
    half_t* we1h = (half_t*)(ws + OFF_WE1);
    half_t* we2h = (half_t*)(ws + OFF_WE2);
    half_t* we3h = (half_t*)(ws + OFF_WE3);
    half_t* wd1h = (half_t*)(ws + OFF_WD1);
    half_t* wd2h = (half_t*)(ws + OFF_WD2);
    half_t* wd3h = (half_t*)(ws + OFF_WD3);
    float*  out  = (float*)d_out;

    // deterministic bucket permutation (no atomics)
    rank_kernel<<<NBLK, 256, 0, stream>>>(seq, rankb, blkt);
    base_kernel<<<1, 64, 0, stream>>>(blkt, meta, blkb);
    finalize_kernel<<<NBLK, 256, 0, stream>>>(seq, rankb, blkb, perm, pos);
    zero_xh_pad<<<dim3(128, NB), 256, 0, stream>>>(meta, xh);
    copy_convert_kernel<<<2048, 256, 0, stream>>>(x, pos, xh);

    // all weight conversions in one launch (16 jobs)
    conv_all<<<dim3(64, 16), 256, 0, stream>>>(Win, Wout, We1, We2, We3, Wd1, Wd2, Wd3, ws);

    // expand: per-bucket K-trimmed GEMM, xh -> E [.,1024]
    gemm_k<1, false><<<dim3(128, 8, NB), 256, 0, stream>>>(xh, winh, bin_, E, nullptr, meta, perm, 0, 1024, 1008);
    // encoder
    gemm_k<0, true ><<<dim3(MT_DENSE, 4), 256, 0, stream>>>(E,    we1h, be1, B512, nullptr, meta, perm, 1024, 512, 512);
    gemm_k<0, true ><<<dim3(MT_DENSE, 2), 256, 0, stream>>>(B512, we2h, be2, C256, nullptr, meta, perm,  512, 256, 256);
    gemm_k<0, false><<<dim3(MT_DENSE, 1), 256, 0, stream>>>(C256, we3h, be3, D128, nullptr, meta, perm,  256, 128, 128);
    // decoder
    gemm_k<0, true ><<<dim3(MT_DENSE, 2), 256, 0, stream>>>(D128, wd1h, bd1, C256, nullptr, meta, perm,  128, 256, 256);
    gemm_k<0, true ><<<dim3(MT_DENSE, 4), 256, 0, stream>>>(C256, wd2h, bd2, B512, nullptr, meta, perm,  256, 512, 512);
    gemm_k<0, false><<<dim3(MT_DENSE, 8), 256, 0, stream>>>(B512, wd3h, bd3, E,    nullptr, meta, perm,  512, 1024, 1008);
    // contract: per-bucket GEMM; bias-only tiles cover cols >= s_k -> full d_out
    gemm_k<2, false><<<dim3(128, 8, NB), 256, 0, stream>>>(E, wouth, bout, nullptr, out, meta, perm, 1024, 1024, 1008);
}

// Round 9
// 414.702 us; speedup vs baseline: 1.0276x; 1.0276x over previous
//
#include <hip/hip_runtime.h>

typedef _Float16 half_t;
typedef __attribute__((ext_vector_type(4))) _Float16 half4;
typedef __attribute__((ext_vector_type(8))) _Float16 half8;
typedef __attribute__((ext_vector_type(4))) float f32x4;

#define BATCH  16384
#define BASE   1008
#define BASEP  1024
#define NB     5
#define ROWS_P 17024      // 16384 + 5*128 (segment alignment slack)
#define MT_DENSE 133      // ROWS_P / 128
#define NBLK   64         // BATCH / 256
#define GMAX   768        // 3 blocks/CU * 256 CU

__constant__ int d_sizes[NB] = {36, 72, 144, 288, 1008};
__constant__ int d_ka[NB]    = {64, 96, 160, 288, 1024};   // align32(s)

__device__ __forceinline__ int bucket_of(int s) {
    return (s == 36) ? 0 : (s == 72) ? 1 : (s == 144) ? 2 : (s == 288) ? 3 : 4;
}

// ---------------- ws layout (bytes) ----------------
// meta: [0..4]=cnt, [5..9]=seg_start (128-aligned)
constexpr size_t OFF_META = 0;                                   // 256 B reserved
constexpr size_t OFF_PERM = 256;                                 // ROWS_P ints
constexpr size_t OFF_RANK = OFF_PERM + (size_t)ROWS_P * 4;       // BATCH ints
constexpr size_t OFF_POS  = OFF_RANK + (size_t)BATCH * 4;        // BATCH ints
constexpr size_t OFF_BLKT = OFF_POS  + (size_t)BATCH * 4;        // NBLK*NB ints
constexpr size_t OFF_BLKB = OFF_BLKT + (size_t)NBLK * NB * 4;    // NBLK*NB ints
constexpr size_t OFF_XH   = (OFF_BLKB + (size_t)NBLK * NB * 4 + 255) & ~(size_t)255;
constexpr size_t SZ1024   = (size_t)ROWS_P * 1024 * 2;
constexpr size_t OFF_E    = OFF_XH + SZ1024;                     // fp16 [ROWS_P][1024]
constexpr size_t OFF_B512 = OFF_E + SZ1024;                      // fp16 [ROWS_P][512]
constexpr size_t OFF_C256 = OFF_B512 + (size_t)ROWS_P * 512 * 2; // fp16 [ROWS_P][256]
constexpr size_t OFF_D128 = OFF_C256 + (size_t)ROWS_P * 256 * 2; // fp16 [ROWS_P][128]
constexpr size_t OFF_WIN  = OFF_D128 + (size_t)ROWS_P * 128 * 2; // fp16 [5][1024][1024]
constexpr size_t OFF_WOUT = OFF_WIN  + (size_t)NB * 1024 * 1024 * 2;
constexpr size_t OFF_WE1  = OFF_WOUT + (size_t)NB * 1024 * 1024 * 2; // [512][1024]
constexpr size_t OFF_WE2  = OFF_WE1 + (size_t)512 * 1024 * 2;        // [256][512]
constexpr size_t OFF_WE3  = OFF_WE2 + (size_t)256 * 512 * 2;         // [128][256]
constexpr size_t OFF_WD1  = OFF_WE3 + (size_t)128 * 256 * 2;         // [256][128]
constexpr size_t OFF_WD2  = OFF_WD1 + (size_t)256 * 128 * 2;         // [512][256]
constexpr size_t OFF_WD3  = OFF_WD2 + (size_t)512 * 256 * 2;         // [1024][512]
constexpr size_t WS_NEED  = OFF_WD3 + (size_t)1024 * 512 * 2;        // ~118.4 MiB

// ---------------- deterministic permutation (no atomics anywhere) ----------------
__global__ void rank_kernel(const int* __restrict__ seq, int* __restrict__ rankb,
                            int* __restrict__ blk_tot) {
    __shared__ int wcnt[4][NB];
    __shared__ int wbase[4][NB];
    const int tid = threadIdx.x, lane = tid & 63, wave = tid >> 6;
    const int b = blockIdx.x * 256 + tid;
    const int k = bucket_of(seq[b]);
    unsigned long long same = 0;
#pragma unroll
    for (int kk = 0; kk < NB; kk++) {
        unsigned long long mk = __ballot(k == kk);
        if (lane == 0) wcnt[wave][kk] = __popcll(mk);
        if (k == kk) same = mk;
    }
    const int lr = __popcll(same & ((1ull << lane) - 1ull));
    __syncthreads();
    if (tid < NB) {                       // tid = bucket index
        int s = 0;
#pragma unroll
        for (int w = 0; w < 4; w++) { wbase[w][tid] = s; s += wcnt[w][tid]; }
        blk_tot[blockIdx.x * NB + tid] = s;
    }
    __syncthreads();
    rankb[b] = wbase[wave][k] + lr;
}

__global__ void base_kernel(const int* __restrict__ blk_tot, int* __restrict__ meta,
                            int* __restrict__ blkbase) {
    __shared__ int tot[NB], seg[NB];
    const int tid = threadIdx.x;
    if (tid < NB) {
        int s = 0;
        for (int blk = 0; blk < NBLK; blk++) {
            blkbase[blk * NB + tid] = s;
            s += blk_tot[blk * NB + tid];
        }
        tot[tid] = s;
    }
    __syncthreads();
    if (tid == 0) {
        int off = 0;
        for (int kk = 0; kk < NB; kk++) {
            seg[kk] = off;
            meta[kk] = tot[kk];
            meta[5 + kk] = off;
            off += (tot[kk] + 127) & ~127;
        }
    }
    __syncthreads();
    if (tid < NB)
        for (int blk = 0; blk < NBLK; blk++) blkbase[blk * NB + tid] += seg[tid];
}

__global__ void finalize_kernel(const int* __restrict__ seq, const int* __restrict__ rankb,
                                const int* __restrict__ blkbase, int* __restrict__ perm,
                                int* __restrict__ pos) {
    const int b = blockIdx.x * 256 + threadIdx.x;
    const int k = bucket_of(seq[b]);
    const int p = blkbase[blockIdx.x * NB + k] + rankb[b];
    perm[p] = b;
    pos[b] = p;
}

// Zero xh segment-padding rows so no GEMM input is ever read-before-write.
__global__ void zero_xh_pad(const int* __restrict__ meta, half_t* __restrict__ xh) {
    const int kb = blockIdx.y;
    const int cnt = meta[kb];
    const int cnt_pad = (cnt + 127) & ~127;
    const int r = cnt + blockIdx.x;
    if (r >= cnt_pad) return;
    const int row = meta[5 + kb] + r;
    half4 z; z.x = z.y = z.z = z.w = (half_t)0.0f;
    *reinterpret_cast<half4*>(xh + (size_t)row * BASEP + threadIdx.x * 4) = z;
}

// Pure coalesced convert+scatter: no atomics, no syncthreads.
__global__ void copy_convert_kernel(const float* __restrict__ x, const int* __restrict__ pos,
                                    half_t* __restrict__ xh) {
    for (int b = blockIdx.x; b < BATCH; b += gridDim.x) {
        int p = pos[b];
        int c = threadIdx.x * 4;  // 0..1020
        half4 o4;
        if (c < BASE) {
            float4 v = *reinterpret_cast<const float4*>(x + (size_t)b * BASE + c);
            o4.x = (half_t)v.x; o4.y = (half_t)v.y; o4.z = (half_t)v.z; o4.w = (half_t)v.w;
        } else {
            o4.x = o4.y = o4.z = o4.w = (half_t)0.0f;
        }
        *reinterpret_cast<half4*>(xh + (size_t)p * BASEP + c) = o4;
    }
}

// ONE fused weight-conversion kernel: 16 jobs (Win x5, Wout x5, 6 dense mats).
__global__ void conv_all(const float* __restrict__ Win, const float* __restrict__ Wout,
                         const float* __restrict__ We1, const float* __restrict__ We2,
                         const float* __restrict__ We3, const float* __restrict__ Wd1,
                         const float* __restrict__ Wd2, const float* __restrict__ Wd3,
                         char* __restrict__ ws) {
    const int j = blockIdx.y;
    const float* src; half_t* dst; int R, C, cshift, climit, rlimit;
    if (j < 5) {
        src = Win + (size_t)j * 1008 * 1008;
        dst = (half_t*)(ws + OFF_WIN) + (size_t)j * 1024 * 1024;
        R = 1008; C = 1008; cshift = 10; climit = d_ka[j]; rlimit = 1024;
    } else if (j < 10) {
        int z = j - 5;
        src = Wout + (size_t)z * 1008 * 1008;
        dst = (half_t*)(ws + OFF_WOUT) + (size_t)z * 1024 * 1024;
        R = 1008; C = 1008; cshift = 10; climit = 1024; rlimit = (d_sizes[z] + 127) & ~127;
    } else {
        switch (j) {
        case 10: src = We1; dst = (half_t*)(ws + OFF_WE1); R = 512;  C = 1008; cshift = 10; rlimit = 512;  break;
        case 11: src = We2; dst = (half_t*)(ws + OFF_WE2); R = 256;  C = 512;  cshift = 9;  rlimit = 256;  break;
        case 12: src = We3; dst = (half_t*)(ws + OFF_WE3); R = 128;  C = 256;  cshift = 8;  rlimit = 128;  break;
        case 13: src = Wd1; dst = (half_t*)(ws + OFF_WD1); R = 256;  C = 128;  cshift = 7;  rlimit = 256;  break;
        case 14: src = Wd2; dst = (half_t*)(ws + OFF_WD2); R = 512;  C = 256;  cshift = 8;  rlimit = 512;  break;
        default: src = Wd3; dst = (half_t*)(ws + OFF_WD3); R = 1008; C = 512;  cshift = 9;  rlimit = 1024; break;
        }
        climit = 1 << cshift;
    }
    const int Cp = 1 << cshift;
    const int total = rlimit << cshift;
    for (int i = blockIdx.x * blockDim.x + threadIdx.x; i < total; i += gridDim.x * blockDim.x) {
        int r = i >> cshift, c = i & (Cp - 1);
        if (c >= climit) continue;
        float v = (r < R && c < C) ? src[(size_t)r * C + c] : 0.0f;
        dst[i] = (half_t)v;
    }
}

// ---------------- GEMM ----------------
// PERSISTENT-GRID version: 1-D grid of <= 768 blocks (3/CU resident,
// __launch_bounds__(256,3)); each block strides a flat tile list. Per tile:
// 128x128 tile, BK=32, 4 waves, 3-buffer LDS pipeline, depth-2 prefetch,
// counted vmcnt, ONE raw s_barrier per K-step, T2 both-sides XOR swizzle.
// End-of-tile __syncthreads() drains vmcnt -> clean slate for next tile's
// counted waits, and protects LDS from the next prologue.
// MODE 0: dense  MODE 1: expand (per-bucket K=ka, NT=8)
// MODE 2: contract (scatter fp32 into memset-zeroed d_out; tiles only where
//         ntile*128 < align128(s_k))
template <int MODE, bool RELU>
__global__ __launch_bounds__(256, 3)
void gemm_k(const half_t* __restrict__ Abase, const half_t* __restrict__ Wbase,
            const float* __restrict__ biasbase, half_t* __restrict__ Obase,
            float* __restrict__ out32, const int* __restrict__ meta,
            const int* __restrict__ perm, int Kdense, int Npad, int Nreal, int NT) {
    const int tid  = threadIdx.x;
    const int lane = tid & 63;
    const int wave = tid >> 6;

    const int wr = (wave >> 1) * 64;   // wave's row quadrant
    const int wc = (wave & 1) * 64;    // wave's col quadrant
    const int fr = lane & 15;
    const int kc = lane >> 4;          // k-chunk 0..3
    const int kcs = (kc ^ ((fr >> 1) & 3)) * 8;  // swizzled half-offset in row
    const int wbase = tid & ~63;       // linear idx of lane0 of this wave

    __shared__ __align__(16) half_t As[3][128 * 32];
    __shared__ __align__(16) half_t Bs[3][128 * 32];

    for (int t = blockIdx.x; ; t += gridDim.x) {
        // ---- decode flat tile id -> (bucket, mtile, ntile) ----
        int mtile, ntile, kb = 0, cnt = 0;
        if (MODE == 0) {
            if (t >= MT_DENSE * NT) break;
            mtile = t % MT_DENSE; ntile = t / MT_DENSE;
        } else {
            int rem = t; bool found = false;
            for (kb = 0; kb < NB; kb++) {
                cnt = meta[kb];
                int mt = (cnt + 127) >> 7;
                int ntk = (MODE == 1) ? NT : ((d_sizes[kb] + 127) >> 7);
                if (rem < mt * ntk) { mtile = rem % mt; ntile = rem / mt; found = true; break; }
                rem -= mt * ntk;
            }
            if (!found) break;
        }

        int K, ld, rowbase;
        const half_t* A;
        const half_t* W;
        const float* bias;
        if (MODE == 0) {
            K = Kdense; ld = Kdense;
            rowbase = mtile * 128;
            A = Abase + (size_t)rowbase * ld;
            W = Wbase + (size_t)ntile * 128 * ld;
            bias = biasbase;
        } else {
            ld = BASEP;
            K = (MODE == 1) ? d_ka[kb] : BASEP;
            rowbase = meta[5 + kb] + mtile * 128;
            A = Abase + (size_t)rowbase * BASEP;
            W = Wbase + (size_t)kb * BASEP * BASEP + (size_t)ntile * 128 * BASEP;
            bias = biasbase + kb * BASE;
        }

        f32x4 acc[4][4];
#pragma unroll
        for (int m = 0; m < 4; m++)
#pragma unroll
            for (int n = 0; n < 4; n++)
                acc[m][n] = (f32x4){0.f, 0.f, 0.f, 0.f};

        // Each STAGE = exactly 4 global_load_lds instructions per wave.
        // Global source column pre-swizzled (T2 both-sides, rule 21).
#define STAGE(buf, kk)                                                                        \
    do {                                                                                      \
        _Pragma("unroll")                                                                     \
        for (int i_ = 0; i_ < 2; i_++) {                                                      \
            int idx_ = i_ * 256 + tid;                                                        \
            int row_ = idx_ >> 2;                                                             \
            int chs_ = (idx_ & 3) ^ ((idx_ >> 3) & 3);                                        \
            const half_t* ga_ = A + (size_t)row_ * ld + ((kk) + chs_ * 8);                    \
            const half_t* gb_ = W + (size_t)row_ * ld + ((kk) + chs_ * 8);                    \
            half_t* la_ = &As[buf][(size_t)(i_ * 256 + wbase) * 8];                           \
            half_t* lb_ = &Bs[buf][(size_t)(i_ * 256 + wbase) * 8];                           \
            __builtin_amdgcn_global_load_lds((__attribute__((address_space(1))) void*)(ga_),  \
                                             (__attribute__((address_space(3))) void*)(la_),  \
                                             16, 0, 0);                                       \
            __builtin_amdgcn_global_load_lds((__attribute__((address_space(1))) void*)(gb_),  \
                                             (__attribute__((address_space(3))) void*)(lb_),  \
                                             16, 0, 0);                                       \
        }                                                                                     \
    } while (0)

        const int NI = K >> 5;             // K/32 iterations
        STAGE(0, 0);
        if (NI > 1) STAGE(1, 32);

        int cur = 0;
        for (int i = 0; i < NI; i++) {
            // counted wait: my tile-i loads done (4 = tile i+1's may remain)
            if (i + 1 < NI) asm volatile("s_waitcnt vmcnt(4)" ::: "memory");
            else            asm volatile("s_waitcnt vmcnt(0)" ::: "memory");
            __builtin_amdgcn_s_barrier();          // all waves' tile-i loads landed
            asm volatile("" ::: "memory");         // pin LDS reads below the barrier

            half8 af[4], bf[4];
#pragma unroll
            for (int m = 0; m < 4; m++)
                af[m] = *reinterpret_cast<const half8*>(&As[cur][(wr + m * 16 + fr) * 32 + kcs]);
#pragma unroll
            for (int n = 0; n < 4; n++)
                bf[n] = *reinterpret_cast<const half8*>(&Bs[cur][(wc + n * 16 + fr) * 32 + kcs]);
#pragma unroll
            for (int m = 0; m < 4; m++)
#pragma unroll
                for (int n = 0; n < 4; n++)
                    acc[m][n] = __builtin_amdgcn_mfma_f32_16x16x32_f16(af[m], bf[n], acc[m][n], 0, 0, 0);

            if (i + 2 < NI) {
                int nxt = cur + 2; if (nxt >= 3) nxt -= 3;
                STAGE(nxt, (i + 2) * 32);          // overwrites tile i-1's buffer (safe)
            }
            cur = (cur + 1 == 3) ? 0 : cur + 1;
        }
#undef STAGE

        // epilogue: D row = (lane>>4)*4 + j, col = lane&15
        float bv[4];
#pragma unroll
        for (int n = 0; n < 4; n++) {
            int col = ntile * 128 + wc + n * 16 + fr;
            bv[n] = (col < Nreal) ? bias[col] : 0.0f;
        }
#pragma unroll
        for (int m = 0; m < 4; m++) {
#pragma unroll
            for (int j = 0; j < 4; j++) {
                int r = wr + m * 16 + kc * 4 + j;
#pragma unroll
                for (int n = 0; n < 4; n++) {
                    float v = acc[m][n][j] + bv[n];
                    if (RELU) v = fmaxf(v, 0.0f);
                    int c = wc + n * 16 + fr;
                    if (MODE == 2) {
                        if (mtile * 128 + r < cnt) {
                            int col = ntile * 128 + c;
                            if (col < BASE) {
                                int orig = perm[rowbase + r];
                                out32[(size_t)orig * BASE + col] = v;
                            }
                        }
                    } else {
                        Obase[(size_t)(rowbase + r) * Npad + ntile * 128 + c] = (half_t)v;
                    }
                }
            }
        }
        __syncthreads();   // drain vmcnt (clean counted-wait slate) + LDS reuse fence
    }
}

// ---------------- launch ----------------
extern "C" void kernel_launch(void* const* d_in, const int* in_sizes, int n_in,
                              void* d_out, int out_size, void* d_ws, size_t ws_size,
                              hipStream_t stream) {
    (void)in_sizes; (void)n_in;
    if (ws_size < WS_NEED) return;

    const float* x    = (const float*)d_in[0];
    const int*   seq  = (const int*)d_in[1];
    const float* Win  = (const float*)d_in[2];
    const float* bin_ = (const float*)d_in[3];
    const float* Wout = (const float*)d_in[4];
    const float* bout = (const float*)d_in[5];
    const float* We1  = (const float*)d_in[6];  const float* be1 = (const float*)d_in[7];
    const float* We2  = (const float*)d_in[8];  const float* be2 = (const float*)d_in[9];
    const float* We3  = (const float*)d_in[10]; const float* be3 = (const float*)d_in[11];
    const float* Wd1  = (const float*)d_in[12]; const float* bd1 = (const float*)d_in[13];
    const float* Wd2  = (const float*)d_in[14]; const float* bd2 = (const float*)d_in[15];
    const float* Wd3  = (const float*)d_in[16]; const float* bd3 = (const float*)d_in[17];

    char* ws = (char*)d_ws;
    int*    meta   = (int*)(ws + OFF_META);
    int*    perm   = (int*)(ws + OFF_PERM);
    int*    rankb  = (int*)(ws + OFF_RANK);
    int*    pos    = (int*)(ws + OFF_POS);
    int*    blkt   = (int*)(ws + OFF_BLKT);
    int*    blkb   = (int*)(ws + OFF_BLKB);
    half_t* xh   = (half_t*)(ws + OFF_XH);
    half_t* E    = (half_t*)(ws + OFF_E);
    half_t* B512 = (half_t*)(ws + OFF_B512);
    half_t* C256 = (half_t*)(ws + OFF_C256);
    half_t* D128 = (half_t*)(ws + OFF_D128);
    half_t* winh = (half_t*)(ws + OFF_WIN);
    half_t* wouth= (half_t*)(ws + OFF_WOUT);
    half_t* we1h = (half_t*)(ws + OFF_WE1);
    half_t* we2h = (half_t*)(ws + OFF_WE2);
    half_t* we3h = (half_t*)(ws + OFF_WE3);
    half_t* wd1h = (half_t*)(ws + OFF_WD1);
    half_t* wd2h = (half_t*)(ws + OFF_WD2);
    half_t* wd3h = (half_t*)(ws + OFF_WD3);
    float*  out  = (float*)d_out;

    hipMemsetAsync(d_out, 0, (size_t)out_size * sizeof(float), stream);

    // deterministic bucket permutation (no atomics)
    rank_kernel<<<NBLK, 256, 0, stream>>>(seq, rankb, blkt);
    base_kernel<<<1, 64, 0, stream>>>(blkt, meta, blkb);
    finalize_kernel<<<NBLK, 256, 0, stream>>>(seq, rankb, blkb, perm, pos);
    zero_xh_pad<<<dim3(128, NB), 256, 0, stream>>>(meta, xh);
    copy_convert_kernel<<<2048, 256, 0, stream>>>(x, pos, xh);

    // all weight conversions in one launch (16 jobs)
    conv_all<<<dim3(64, 16), 256, 0, stream>>>(Win, Wout, We1, We2, We3, Wd1, Wd2, Wd3, ws);

    // expand: per-bucket K-trimmed GEMM, xh -> E [.,1024]  (max tiles 1024)
    gemm_k<1, false><<<GMAX, 256, 0, stream>>>(xh, winh, bin_, E, nullptr, meta, perm, 0, 1024, 1008, 8);
    // encoder
    gemm_k<0, true ><<<532, 256, 0, stream>>>(E,    we1h, be1, B512, nullptr, meta, perm, 1024, 512, 512, 4);
    gemm_k<0, true ><<<266, 256, 0, stream>>>(B512, we2h, be2, C256, nullptr, meta, perm,  512, 256, 256, 2);
    gemm_k<0, false><<<133, 256, 0, stream>>>(C256, we3h, be3, D128, nullptr, meta, perm,  256, 128, 128, 1);
    // decoder
    gemm_k<0, true ><<<266, 256, 0, stream>>>(D128, wd1h, bd1, C256, nullptr, meta, perm,  128, 256, 256, 2);
    gemm_k<0, true ><<<532, 256, 0, stream>>>(C256, wd2h, bd2, B512, nullptr, meta, perm,  256, 512, 512, 4);
    gemm_k<0, false><<<GMAX, 256, 0, stream>>>(B512, wd3h, bd3, E,    nullptr, meta, perm,  512, 1024, 1008, 8);
    // contract: per-bucket GEMM over cols < align128(s_k); scatter into zeroed d_out
    gemm_k<2, false><<<GMAX, 256, 0, stream>>>(E, wouth, bout, nullptr, out, meta, perm, 1024, 1024, 1008, 0);
}